// Round 1
// baseline (332.770 us; speedup 1.0000x reference)
//
#include <hip/hip_runtime.h>
#include <hip/hip_bf16.h>

typedef __attribute__((ext_vector_type(8))) short bf16x8;
typedef __attribute__((ext_vector_type(4))) float f32x4;

__device__ __forceinline__ short f2b(float x) {
    __hip_bfloat16 h = __float2bfloat16(x);
    short s;
    __builtin_memcpy(&s, &h, 2);
    return s;
}

// ---------------- fp32 -> bf16 convert (vectorized) ----------------
__global__ __launch_bounds__(256) void k_cvt(const float* __restrict__ src,
                                             short* __restrict__ dst, int n4) {
    int i = blockIdx.x * 256 + threadIdx.x;
    if (i >= n4) return;
    float4 v = ((const float4*)src)[i];
    short4 o;
    o.x = f2b(v.x); o.y = f2b(v.y); o.z = f2b(v.z); o.w = f2b(v.w);
    ((short4*)dst)[i] = o;
}

// ---------------- memory rows + zero pads ----------------
// i in [0, 131072): writes m_k*8 / m_v*8 rows, zeroes kcat pad rows and vt pad cols
__global__ __launch_bounds__(256) void k_aux(const float* __restrict__ mk,
                                             const float* __restrict__ mv,
                                             short* __restrict__ kcat,
                                             short* __restrict__ vcat,
                                             short* __restrict__ vt) {
    int i = blockIdx.x * 256 + threadIdx.x;
    int b = i >> 16;
    int r = (i >> 10) & 63;
    int d = i & 1023;
    kcat[((size_t)(b * 2176 + 2048 + r)) * 1024 + d] = f2b(mk[r * 1024 + d] * 8.0f);
    vcat[((size_t)(b * 2176 + 2048 + r)) * 1024 + d] = f2b(mv[r * 1024 + d] * 8.0f);
    kcat[((size_t)(b * 2176 + 2112 + r)) * 1024 + d] = 0;
    int h = (i >> 12) & 15, dd = (i >> 6) & 63, c = i & 63;
    vt[((size_t)((b * 16 + h) * 64 + dd)) * 2176 + 2112 + c] = 0;
}

// ---------------- bf16 NT GEMM: C[r][o] = sum_k A[r][k]*W[o][k] + bias[o] ----------------
// M=4096 (grid.x=32), N=1024 (grid.y=8), K=1024. 128x128 tile, BK=32, 4 waves.
// MODE 0: bf16 out, direct [row*1024+col]
// MODE 1: bf16 out, row remap to concat buffer [(b*2176 + n)*1024 + col]
// MODE 2: fp32 out + bias -> d_out
template <int MODE>
__global__ __launch_bounds__(256) void gemm_nt(const short* __restrict__ A,
                                               const short* __restrict__ Bw,
                                               const float* __restrict__ bias,
                                               void* __restrict__ Cout) {
    __shared__ __align__(16) short As[128][40];  // pad: stride 80B, 16B-aligned, conflict-free
    __shared__ __align__(16) short Bs[128][40];
    const int tid = threadIdx.x;
    const int bm = blockIdx.x, bn = blockIdx.y;
    const int w = tid >> 6, lane = tid & 63;
    const int wm = w >> 1, wn = w & 1;
    const int lr = lane & 15, lg = lane >> 4;
    const int srow = tid >> 2, schunk = tid & 3;

    f32x4 acc[4][4] = {};

    for (int k0 = 0; k0 < 1024; k0 += 32) {
        __syncthreads();
        #pragma unroll
        for (int i = 0; i < 2; ++i) {
            int r = srow + i * 64;
            bf16x8 av = *(const bf16x8*)(A + (size_t)(bm * 128 + r) * 1024 + k0 + schunk * 8);
            *(bf16x8*)(&As[r][schunk * 8]) = av;
            bf16x8 bv = *(const bf16x8*)(Bw + (size_t)(bn * 128 + r) * 1024 + k0 + schunk * 8);
            *(bf16x8*)(&Bs[r][schunk * 8]) = bv;
        }
        __syncthreads();
        bf16x8 af[4], bfr[4];
        #pragma unroll
        for (int m = 0; m < 4; ++m) af[m] = *(const bf16x8*)(&As[wm * 64 + m * 16 + lr][lg * 8]);
        #pragma unroll
        for (int n = 0; n < 4; ++n) bfr[n] = *(const bf16x8*)(&Bs[wn * 64 + n * 16 + lr][lg * 8]);
        #pragma unroll
        for (int m = 0; m < 4; ++m)
            #pragma unroll
            for (int n = 0; n < 4; ++n)
                acc[m][n] = __builtin_amdgcn_mfma_f32_16x16x32_bf16(af[m], bfr[n], acc[m][n], 0, 0, 0);
    }

    #pragma unroll
    for (int m = 0; m < 4; ++m) {
        #pragma unroll
        for (int n = 0; n < 4; ++n) {
            int col = bn * 128 + wn * 64 + n * 16 + lr;
            float bv = bias[col];
            #pragma unroll
            for (int r = 0; r < 4; ++r) {
                int row = bm * 128 + wm * 64 + m * 16 + lg * 4 + r;
                float val = acc[m][n][r] + bv;
                if (MODE == 0) {
                    ((short*)Cout)[(size_t)row * 1024 + col] = f2b(val);
                } else if (MODE == 1) {
                    int rr = (row >> 11) * 2176 + (row & 2047);
                    ((short*)Cout)[(size_t)rr * 1024 + col] = f2b(val);
                } else {
                    ((float*)Cout)[(size_t)row * 1024 + col] = val;
                }
            }
        }
    }
}

// ---------------- per-head V transpose: vt[(b*16+h)*64 + d][kk] = vcat[b][kk][h*64+d] ----------------
__global__ __launch_bounds__(256) void k_vtrans(const short* __restrict__ vcat,
                                                short* __restrict__ vt) {
    __shared__ __align__(16) short t[64][72];
    const int kk0 = blockIdx.x * 64, h = blockIdx.y, b = blockIdx.z;
    const int tid = threadIdx.x;
    const int r = tid >> 3, c = tid & 7;
    #pragma unroll
    for (int i = 0; i < 2; ++i) {
        int row = r + i * 32;
        bf16x8 v = *(const bf16x8*)(vcat + ((size_t)(b * 2176 + kk0 + row)) * 1024 + h * 64 + c * 8);
        *(bf16x8*)(&t[row][c * 8]) = v;
    }
    __syncthreads();
    #pragma unroll
    for (int i = 0; i < 2; ++i) {
        int d = r + i * 32;
        bf16x8 outv;
        #pragma unroll
        for (int j = 0; j < 8; ++j) outv[j] = t[c * 8 + j][d];
        *(bf16x8*)(vt + ((size_t)((b * 16 + h) * 64 + d)) * 2176 + kk0 + c * 8) = outv;
    }
}

// ---------------- flash attention: grid (16 qtiles, 16 heads, 2 batch), 4 waves ----------------
__global__ __launch_bounds__(256) void k_attn(const short* __restrict__ qp,
                                              const short* __restrict__ kcat,
                                              const short* __restrict__ vt,
                                              const int* __restrict__ maskI,
                                              short* __restrict__ aout) {
    __shared__ float smask[2176];
    __shared__ __align__(16) short Pt[4][32][136];

    const int qt = blockIdx.x, h = blockIdx.y, b = blockIdx.z;
    const int tid = threadIdx.x;
    const int w = tid >> 6, lane = tid & 63;
    const int lr = lane & 15, lg = lane >> 4;

    for (int i = tid; i < 2176; i += 256) {
        float mval;
        if (i < 2048)       mval = maskI[b * 2048 + i] ? -INFINITY : 0.0f;
        else if (i < 2112)  mval = 0.0f;   // memory slots: never masked
        else                mval = -INFINITY;  // tail pad of last key tile
        smask[i] = mval;
    }
    __syncthreads();

    // Q fragments held in registers for the whole kernel
    const size_t qbase = ((size_t)(b * 2048 + qt * 128 + w * 32)) * 1024 + h * 64;
    bf16x8 qf[2][2];
    #pragma unroll
    for (int m = 0; m < 2; ++m)
        #pragma unroll
        for (int ks = 0; ks < 2; ++ks)
            qf[m][ks] = *(const bf16x8*)(qp + qbase + (size_t)(m * 16 + lr) * 1024 + ks * 32 + lg * 8);

    float m_run[2][4], l_run[2][4];
    f32x4 o[2][4] = {};
    #pragma unroll
    for (int m = 0; m < 2; ++m)
        #pragma unroll
        for (int r = 0; r < 4; ++r) { m_run[m][r] = -1e30f; l_run[m][r] = 0.0f; }

    for (int kt = 0; kt < 17; ++kt) {
        const int key0 = kt * 128;
        // S = Q K^T
        f32x4 s[2][8] = {};
        #pragma unroll
        for (int ks = 0; ks < 2; ++ks) {
            #pragma unroll
            for (int n = 0; n < 8; ++n) {
                bf16x8 kf = *(const bf16x8*)(kcat +
                    ((size_t)(b * 2176 + key0 + n * 16 + lr)) * 1024 + h * 64 + ks * 32 + lg * 8);
                s[0][n] = __builtin_amdgcn_mfma_f32_16x16x32_bf16(qf[0][ks], kf, s[0][n], 0, 0, 0);
                s[1][n] = __builtin_amdgcn_mfma_f32_16x16x32_bf16(qf[1][ks], kf, s[1][n], 0, 0, 0);
            }
        }
        float madd[8];
        #pragma unroll
        for (int n = 0; n < 8; ++n) madd[n] = smask[key0 + n * 16 + lr];

        // online softmax (row stats: reduce over lanes 0..15 of each 16-lane group)
        #pragma unroll
        for (int m = 0; m < 2; ++m) {
            #pragma unroll
            for (int r = 0; r < 4; ++r) {
                float sv[8];
                float mx = m_run[m][r];
                #pragma unroll
                for (int n = 0; n < 8; ++n) {
                    sv[n] = s[m][n][r] * 0.125f + madd[n];
                    mx = fmaxf(mx, sv[n]);
                }
                #pragma unroll
                for (int off = 1; off < 16; off <<= 1) mx = fmaxf(mx, __shfl_xor(mx, off));
                float corr = __expf(m_run[m][r] - mx);
                float rs = 0.0f;
                #pragma unroll
                for (int n = 0; n < 8; ++n) {
                    float pv = __expf(sv[n] - mx);
                    s[m][n][r] = pv;
                    rs += pv;
                }
                #pragma unroll
                for (int off = 1; off < 16; off <<= 1) rs += __shfl_xor(rs, off);
                m_run[m][r] = mx;
                l_run[m][r] = l_run[m][r] * corr + rs;
                #pragma unroll
                for (int nO = 0; nO < 4; ++nO) o[m][nO][r] *= corr;
            }
        }

        // P (D-layout) -> LDS -> A-fragments. Wave-private rows: no barrier needed.
        #pragma unroll
        for (int m = 0; m < 2; ++m)
            #pragma unroll
            for (int n = 0; n < 8; ++n)
                #pragma unroll
                for (int r = 0; r < 4; ++r)
                    Pt[w][m * 16 + lg * 4 + r][n * 16 + lr] = f2b(s[m][n][r]);

        // O += P V
        #pragma unroll
        for (int ks2 = 0; ks2 < 4; ++ks2) {
            bf16x8 pa[2];
            pa[0] = *(const bf16x8*)(&Pt[w][lr][ks2 * 32 + lg * 8]);
            pa[1] = *(const bf16x8*)(&Pt[w][16 + lr][ks2 * 32 + lg * 8]);
            #pragma unroll
            for (int nO = 0; nO < 4; ++nO) {
                bf16x8 vf = *(const bf16x8*)(vt +
                    ((size_t)((b * 16 + h) * 64 + nO * 16 + lr)) * 2176 + key0 + ks2 * 32 + lg * 8);
                o[0][nO] = __builtin_amdgcn_mfma_f32_16x16x32_bf16(pa[0], vf, o[0][nO], 0, 0, 0);
                o[1][nO] = __builtin_amdgcn_mfma_f32_16x16x32_bf16(pa[1], vf, o[1][nO], 0, 0, 0);
            }
        }
    }

    #pragma unroll
    for (int m = 0; m < 2; ++m) {
        #pragma unroll
        for (int r = 0; r < 4; ++r) {
            float inv = 1.0f / l_run[m][r];
            int qrow = qt * 128 + w * 32 + m * 16 + lg * 4 + r;
            #pragma unroll
            for (int nO = 0; nO < 4; ++nO)
                aout[((size_t)(b * 2048 + qrow)) * 1024 + h * 64 + nO * 16 + lr] =
                    f2b(o[m][nO][r] * inv);
        }
    }
}

extern "C" void kernel_launch(void* const* d_in, const int* in_sizes, int n_in,
                              void* d_out, int out_size, void* d_ws, size_t ws_size,
                              hipStream_t stream) {
    const float* q  = (const float*)d_in[0];
    const float* k  = (const float*)d_in[1];
    const float* v  = (const float*)d_in[2];
    const int* mask = (const int*)d_in[3];
    const float* Wq = (const float*)d_in[4];
    const float* bq = (const float*)d_in[5];
    const float* Wk = (const float*)d_in[6];
    const float* bk = (const float*)d_in[7];
    const float* Wv = (const float*)d_in[8];
    const float* bv = (const float*)d_in[9];
    const float* Wo = (const float*)d_in[10];
    const float* bo = (const float*)d_in[11];
    const float* mk = (const float*)d_in[12];
    const float* mv = (const float*)d_in[13];

    char* ws = (char*)d_ws;
    size_t off = 0;
    auto alloc = [&](size_t bytes) {
        char* p = ws + off;
        off += (bytes + 255) & ~(size_t)255;
        return p;
    };
    short* qb   = (short*)alloc(4096ull * 1024 * 2);
    short* kb   = (short*)alloc(4096ull * 1024 * 2);
    short* vb   = (short*)alloc(4096ull * 1024 * 2);
    short* Wqb  = (short*)alloc(1024ull * 1024 * 2);
    short* Wkb  = (short*)alloc(1024ull * 1024 * 2);
    short* Wvb  = (short*)alloc(1024ull * 1024 * 2);
    short* Wob  = (short*)alloc(1024ull * 1024 * 2);
    short* qp   = (short*)alloc(4096ull * 1024 * 2);
    short* kcat = (short*)alloc(2ull * 2176 * 1024 * 2);
    short* vcat = (short*)alloc(2ull * 2176 * 1024 * 2);
    short* vtb  = (short*)alloc(2ull * 16 * 64 * 2176 * 2);
    short* aout = (short*)alloc(4096ull * 1024 * 2);

    k_cvt<<<4096, 256, 0, stream>>>(q, qb, 1048576);
    k_cvt<<<4096, 256, 0, stream>>>(k, kb, 1048576);
    k_cvt<<<4096, 256, 0, stream>>>(v, vb, 1048576);
    k_cvt<<<1024, 256, 0, stream>>>(Wq, Wqb, 262144);
    k_cvt<<<1024, 256, 0, stream>>>(Wk, Wkb, 262144);
    k_cvt<<<1024, 256, 0, stream>>>(Wv, Wvb, 262144);
    k_cvt<<<1024, 256, 0, stream>>>(Wo, Wob, 262144);
    k_aux<<<512, 256, 0, stream>>>(mk, mv, kcat, vcat, vtb);

    gemm_nt<0><<<dim3(32, 8), 256, 0, stream>>>(qb, Wqb, bq, qp);
    gemm_nt<1><<<dim3(32, 8), 256, 0, stream>>>(kb, Wkb, bk, kcat);
    gemm_nt<1><<<dim3(32, 8), 256, 0, stream>>>(vb, Wvb, bv, vcat);

    k_vtrans<<<dim3(33, 16, 2), 256, 0, stream>>>(vcat, vtb);

    k_attn<<<dim3(16, 16, 2), 256, 0, stream>>>(qp, kcat, vtb, mask, aout);

    gemm_nt<2><<<dim3(32, 8), 256, 0, stream>>>(aout, Wob, bo, (float*)d_out);
}